// Round 3
// baseline (284.363 us; speedup 1.0000x reference)
//
#include <hip/hip_runtime.h>
#include <math.h>

// B=4096 rows, C=8192 cols, f32. Scalar = mean over (row, positive) pairs of
// log1p(exp(lse_neg(row) - x_p)). weights input unused (cancels).
//
// MLP-first design: block = one row, 512 threads, each thread loads its
// 16 logits + 16 targets into registers FIRST (8 independent dwordx4 loads
// in flight), then computes. No LDS atomics, no branches between loads.
// lse_neg recovered as M + log(S_all - sum_pos exp(x_p - M)).

#define ROWS 4096
#define COLS 8192
#define TPB  512
#define NV   (COLS / (TPB * 4))   // 4 float4 per thread
#define EPT  (NV * 4)             // 16 elements per thread

__global__ __launch_bounds__(TPB) void row_loss_kernel(
        const float* __restrict__ logits,
        const float* __restrict__ target,
        float* __restrict__ ws_loss,
        float* __restrict__ ws_cnt) {
    const int row  = blockIdx.x;
    const int tid  = threadIdx.x;
    const int wave = tid >> 6;
    const int lane = tid & 63;

    const float4* __restrict__ orow =
        (const float4*)(logits + (size_t)row * COLS);
    const float4* __restrict__ trow =
        (const float4*)(target + (size_t)row * COLS);

    // ---- Load phase: all 8 loads issued before any consumption ----
    float4 o4[NV], t4[NV];
#pragma unroll
    for (int i = 0; i < NV; i++) o4[i] = orow[tid + i * TPB];
#pragma unroll
    for (int i = 0; i < NV; i++) t4[i] = trow[tid + i * TPB];

    const float* ov = reinterpret_cast<const float*>(o4);
    const float* tv = reinterpret_cast<const float*>(t4);

    __shared__ float sm[8], ssum[8], ses[8], sloss[8], scnt[8];

    // ---- Phase 1: block max over ALL elements ----
    float m = ov[0];
#pragma unroll
    for (int j = 1; j < EPT; j++) m = fmaxf(m, ov[j]);
#pragma unroll
    for (int off = 32; off > 0; off >>= 1)
        m = fmaxf(m, __shfl_xor(m, off, 64));
    if (lane == 0) sm[wave] = m;
    __syncthreads();
    float M = sm[0];
#pragma unroll
    for (int w = 1; w < 8; w++) M = fmaxf(M, sm[w]);

    // ---- Phase 2: S_all = sum exp(x - M); es = positives-only part ----
    float s = 0.f, es = 0.f;
#pragma unroll
    for (int j = 0; j < EPT; j++) {
        float e = __expf(ov[j] - M);
        s += e;
        es += (tv[j] != 0.f) ? e : 0.f;
    }
#pragma unroll
    for (int off = 32; off > 0; off >>= 1) {
        s  += __shfl_xor(s,  off, 64);
        es += __shfl_xor(es, off, 64);
    }
    if (lane == 0) { ssum[wave] = s; ses[wave] = es; }
    __syncthreads();
    float S = 0.f, ES = 0.f;
#pragma unroll
    for (int w = 0; w < 8; w++) { S += ssum[w]; ES += ses[w]; }
    const float lse_neg = M + __logf(S - ES);

    // ---- Phase 3: loss over positives (values still in registers) ----
    float loss = 0.f, cnt = 0.f;
#pragma unroll
    for (int j = 0; j < EPT; j++) {
        if (tv[j] != 0.f) {
            loss += log1pf(__expf(lse_neg - ov[j]));
            cnt  += 1.f;
        }
    }
#pragma unroll
    for (int off = 32; off > 0; off >>= 1) {
        loss += __shfl_xor(loss, off, 64);
        cnt  += __shfl_xor(cnt,  off, 64);
    }
    if (lane == 0) { sloss[wave] = loss; scnt[wave] = cnt; }
    __syncthreads();
    if (tid == 0) {
        float L = 0.f, N = 0.f;
#pragma unroll
        for (int w = 0; w < 8; w++) { L += sloss[w]; N += scnt[w]; }
        ws_loss[row] = L;
        ws_cnt[row]  = N;
    }
}

__global__ __launch_bounds__(256) void finalize_kernel(
        const float* __restrict__ ws_loss,
        const float* __restrict__ ws_cnt,
        float* __restrict__ out) {
    const int tid = threadIdx.x;
    float l = 0.f, c = 0.f;
    for (int i = tid; i < ROWS; i += 256) {
        l += ws_loss[i];
        c += ws_cnt[i];
    }
#pragma unroll
    for (int off = 32; off > 0; off >>= 1) {
        l += __shfl_xor(l, off, 64);
        c += __shfl_xor(c, off, 64);
    }
    __shared__ float sl[4], sc[4];
    if ((tid & 63) == 0) { sl[tid >> 6] = l; sc[tid >> 6] = c; }
    __syncthreads();
    if (tid == 0) {
        float L = sl[0] + sl[1] + sl[2] + sl[3];
        float N = sc[0] + sc[1] + sc[2] + sc[3];
        out[0] = L / N;
    }
}

extern "C" void kernel_launch(void* const* d_in, const int* in_sizes, int n_in,
                              void* d_out, int out_size, void* d_ws, size_t ws_size,
                              hipStream_t stream) {
    const float* logits = (const float*)d_in[0];   // [B, C]
    const float* target = (const float*)d_in[1];   // [B, C]
    // d_in[2] (weights) unused: per-sample CE weight cancels.
    float* ws_loss = (float*)d_ws;                 // [ROWS]
    float* ws_cnt  = ws_loss + ROWS;               // [ROWS]

    row_loss_kernel<<<ROWS, TPB, 0, stream>>>(logits, target, ws_loss, ws_cnt);
    finalize_kernel<<<1, 256, 0, stream>>>(ws_loss, ws_cnt, (float*)d_out);
}